// Round 8
// baseline (382.579 us; speedup 1.0000x reference)
//
#include <hip/hip_runtime.h>
#include <stdint.h>

// Problem constants
#define B_  16
#define N_  1024
#define C_  1024
#define H_  16
#define D_  64
#define P_  16
#define M_  1040           // P + N
#define MP_ 1088           // M padded to 17*64

typedef __attribute__((ext_vector_type(8))) short short8;   // 8 bf16 = 4 VGPRs
typedef __attribute__((ext_vector_type(4))) float f32x4;    // MFMA C/D frag

__device__ __forceinline__ unsigned short f2bf(float f) {
  unsigned int u = __float_as_uint(f);
  u += 0x7fffu + ((u >> 16) & 1u);          // RNE
  return (unsigned short)(u >> 16);
}

__device__ __forceinline__ unsigned int cvt_pk_bf16(float lo, float hi) {
  unsigned int r;
  asm("v_cvt_pk_bf16_f32 %0, %1, %2" : "=v"(r) : "v"(lo), "v"(hi));
  return r;
}

// 2^x via the HW transcendental unit (v_exp_f32 IS exp2 on gfx9xx).
__device__ __forceinline__ float exp2_hw(float x) {
  float r;
  asm("v_exp_f32 %0, %1" : "=v"(r) : "v"(x));
  return r;
}

// async global->LDS, 16B per lane. LDS dest must be wave-uniform base (+lane*16 implicit).
__device__ __forceinline__ void async_cp16(void* lds, const void* g) {
  __builtin_amdgcn_global_load_lds(
      (__attribute__((address_space(1))) void*)(void*)g,
      (__attribute__((address_space(3))) void*)lds,
      16, 0, 0);
}

// ---------------- prep kernels (merged: 2 launches) ----------------

// blocks [0,16384): x fp32->bf16 cast.  blocks [16384,20480): K prefix/pad + V^T prefix/pad.
__global__ void prep_kernel(const float* __restrict__ x, const float* __restrict__ pk,
                            const float* __restrict__ pv, unsigned short* __restrict__ xb,
                            unsigned short* __restrict__ Kw, unsigned short* __restrict__ Vt) {
  int bid = blockIdx.x;
  if (bid < 16384) {
    int i = (bid * 256 + threadIdx.x) * 4;
    float4 v = *(const float4*)(x + i);
    ushort4 o;
    o.x = f2bf(v.x); o.y = f2bf(v.y); o.z = f2bf(v.z); o.w = f2bf(v.w);
    *(ushort4*)(xb + i) = o;
  } else {
    int idx = (bid - 16384) * 256 + threadIdx.x;   // 1,048,576
    {  // K: d fastest (coalesced dst + src)
      int d = idx & 63, rr = (idx >> 6) & 63, bh = idx >> 12;
      int row = (rr < P_) ? rr : (1024 + rr);
      float kv = 0.f;
      if (rr < P_) { int b = bh >> 4, h = bh & 15; kv = pk[(b * P_ + rr) * C_ + h * D_ + d]; }
      Kw[((size_t)bh * MP_ + row) * D_ + d] = f2bf(kv);
    }
    {  // V^T: row-slot fastest (coalesced dst; tiny strided src absorbed by L2)
      int mm = idx & 63, d = (idx >> 6) & 63, bh = idx >> 12;
      int row = (mm < P_) ? mm : (1024 + mm);
      float vv = 0.f;
      if (mm < P_) { int b = bh >> 4, h = bh & 15; vv = pv[(b * P_ + mm) * C_ + h * D_ + d]; }
      Vt[((size_t)bh * D_ + d) * MP_ + row] = f2bf(vv);
    }
  }
}

// both weight transposes in one launch: [1024 k][cols n] fp32 -> [n][1024 k] bf16.
// blockIdx.x < 48 -> w_qkv (cols=3072); else w_proj (cols=1024).
__global__ void transpose_cast_kernel(const float* __restrict__ wqkv,
                                      const float* __restrict__ wproj,
                                      unsigned short* __restrict__ oqkv,
                                      unsigned short* __restrict__ oproj) {
  __shared__ unsigned short t[64][68];   // pad 68: breaks bank aliasing on strided read
  int bx = blockIdx.x;
  const float* in;  unsigned short* out;  int cols, n0;
  if (bx < 48) { in = wqkv;  out = oqkv;  cols = 3072; n0 = bx * 64; }
  else         { in = wproj; out = oproj; cols = 1024; n0 = (bx - 48) * 64; }
  int k0 = blockIdx.y * 64;
  int tid = threadIdx.x;
#pragma unroll
  for (int i = 0; i < 16; ++i) {
    int e = i * 256 + tid;
    int kk = e >> 6, nn = e & 63;
    t[kk][nn] = f2bf(in[(size_t)(k0 + kk) * cols + n0 + nn]);
  }
  __syncthreads();
#pragma unroll
  for (int i = 0; i < 16; ++i) {
    int e = i * 256 + tid;
    int nn = e >> 6, kk = e & 63;
    out[(size_t)(n0 + nn) * 1024 + k0 + kk] = t[kk][nn];
  }
}

// ---------------- GEMM: 256x256 tile, BK=32, 16 waves, simple overlap loop ----------
// C[M,Ncols] = A[M,1024] * Bt[Ncols,1024]^T, bf16 in, fp32 acc.
// 1024 threads = 16 waves in a 4x4 grid; wave tile 64x64 -> acc = 64 VGPR/thread, so
// 4 waves/SIMD (16 waves/CU) fit under the 128-VGPR occupancy boundary (2x the waves of
// the 512-thr variant, which stalled at 2 waves/SIMD: MfmaUtil 29%, all pipes idle).
// LDS: S[2 buf][A|B][256 rows x 32 k] = 64 KiB. Loop = the attn-kernel structure:
//   __syncthreads()        // drains vmcnt: buf[kt&1] landed; prior reads done (lgkm 0)
//   STAGE(kt+1 -> buf^1)   // latency hides under the whole tile body
//   8 swizzled ds_read_b128 + 16 MFMA, compiler-scheduled lgkm (near-optimal per m97)
// Race-free: staged buffer's last readers drained at the preceding barrier.
// Chunk swizzle (proven, 0 conflicts): read byte (quad*16)^((l15&6)<<3); staging source
// k-chunk (tid&3)^((tid>>3)&3) with linear LDS dest (global_load_lds).
// MODE 0: qkv epilogue (Q^T scaled by 0.125*log2e, Kw, V^T). MODE 1: +bias, FP32 out.
template <int MODE>
__global__ __launch_bounds__(1024, 4) void gemm256(const unsigned short* __restrict__ A,
                                                   const unsigned short* __restrict__ Bt,
                                                   unsigned short* __restrict__ Qt,
                                                   unsigned short* __restrict__ Kw,
                                                   unsigned short* __restrict__ Vt,
                                                   const float* __restrict__ bias,
                                                   float* __restrict__ Out) {
  __shared__ alignas(16) unsigned short S[2][2][8192];   // [buf][A|B][256r * 32k]

  const int tid = threadIdx.x;
  const int w = tid >> 6, lane = tid & 63;
  const int l15 = lane & 15, quad = lane >> 4;
  const int wm = w >> 2, wn = w & 3;            // 4 x 4 wave grid; wave tile 64m x 64n
  const int rt = blockIdx.x, ct = blockIdx.y;

  // fragment ds_read_b128: row (64B), chunk-swizzled 16B column
  const int qoff = (quad * 16) ^ ((l15 & 6) << 3);
  const int arow = wm * 64, brow = wn * 64;

  // staging: thread tid covers LDS bytes [tid*16, tid*16+16) of a 16KB panel (linear);
  // source row = tid>>2, source k-chunk inverse-swizzled on row bits 1,2 (= tid bits 3,4)
  const int srow = tid >> 2;
  const int sc = (tid & 3) ^ ((tid >> 3) & 3);
  const unsigned short* gA = A + (size_t)(rt * 256 + srow) * 1024 + sc * 8;
  const unsigned short* gB = Bt + (size_t)(ct * 256 + srow) * 1024 + sc * 8;
  const int sbase = w * 512;                    // wave-uniform LDS base (shorts)

  f32x4 acc[4][4] = {};

  // prologue: stage tile 0
  async_cp16(&S[0][0][sbase], gA);
  async_cp16(&S[0][1][sbase], gB);

#pragma unroll 1
  for (int kt = 0; kt < 32; ++kt) {
    __syncthreads();                            // buf[kt&1] landed for all waves
    if (kt + 1 < 32) {                          // stage next tile; hides under body
      async_cp16(&S[(kt + 1) & 1][0][sbase], gA + (kt + 1) * 32);
      async_cp16(&S[(kt + 1) & 1][1][sbase], gB + (kt + 1) * 32);
    }
    const char* Sa = (const char*)&S[kt & 1][0][0];
    const char* Sb = (const char*)&S[kt & 1][1][0];
    short8 a[4], b[4];
#pragma unroll
    for (int mt = 0; mt < 4; ++mt)
      a[mt] = *(const short8*)(Sa + (arow + mt * 16 + l15) * 64 + qoff);
#pragma unroll
    for (int nt = 0; nt < 4; ++nt)
      b[nt] = *(const short8*)(Sb + (brow + nt * 16 + l15) * 64 + qoff);
#pragma unroll
    for (int mt = 0; mt < 4; ++mt)
#pragma unroll
      for (int nt = 0; nt < 4; ++nt)
        acc[mt][nt] = __builtin_amdgcn_mfma_f32_16x16x32_bf16(a[mt], b[nt],
                                                              acc[mt][nt], 0, 0, 0);
  }

  // epilogue: C/D layout col = l15 (B side), row = quad*4 + r (A side)
  if (MODE == 0) {
    const int b = rt >> 2;                       // 256-row tiles align with batches
    const int colg = ct * 4 + wn;                // global 64-col group, 0..47
    const int sel = colg >> 4;                   // 0=Q, 1=K, 2=V
    const int h = colg & 15;
    const int bh = b * 16 + h;
    const int nbase = (rt & 3) * 256 + wm * 64 + quad * 4;   // row within batch
#pragma unroll
    for (int nf = 0; nf < 4; ++nf) {
      const int d = nf * 16 + l15;
#pragma unroll
      for (int mt = 0; mt < 4; ++mt) {
        const int n0 = nbase + mt * 16;
        if (sel == 1) {
          // K: [bh][m][d] layout, lane holds fixed d for 4 consecutive n -> scalar stores
#pragma unroll
          for (int r = 0; r < 4; ++r)
            Kw[((size_t)bh * MP_ + P_ + n0 + r) * D_ + d] = f2bf(acc[mt][nf][r]);
        } else if (sel == 0) {
          // softmax scale * log2(e) folded into Q (attn uses exp2)
          ushort4 p4;
          p4.x = f2bf(acc[mt][nf][0] * 0.18033688f);
          p4.y = f2bf(acc[mt][nf][1] * 0.18033688f);
          p4.z = f2bf(acc[mt][nf][2] * 0.18033688f);
          p4.w = f2bf(acc[mt][nf][3] * 0.18033688f);
          *(ushort4*)&Qt[((size_t)bh * D_ + d) * N_ + n0] = p4;
        } else {
          ushort4 p4;
          p4.x = f2bf(acc[mt][nf][0]);
          p4.y = f2bf(acc[mt][nf][1]);
          p4.z = f2bf(acc[mt][nf][2]);
          p4.w = f2bf(acc[mt][nf][3]);
          *(ushort4*)&Vt[((size_t)bh * D_ + d) * MP_ + P_ + n0] = p4;
        }
      }
    }
  } else {
#pragma unroll
    for (int nf = 0; nf < 4; ++nf) {
      const int col = ct * 256 + wn * 64 + nf * 16 + l15;
      const float bs = bias[col];
#pragma unroll
      for (int mt = 0; mt < 4; ++mt) {
#pragma unroll
        for (int r = 0; r < 4; ++r) {
          const int row = rt * 256 + wm * 64 + mt * 16 + quad * 4 + r;
          Out[(size_t)row * C_ + col] = acc[mt][nf][r] + bs;   // d_out is FP32
        }
      }
    }
  }
}

// ---------------- attention ----------------
// grid (256 bh, 8 qt): bh fastest -> all 8 qt-blocks of one bh on ONE XCD (K/V L2 reuse).
// block 256 = 4 waves x 32 q-rows. Swapped QK^T with PERMUTED K-row feed:
// mfma #ct2 reads K LDS rows perm(ct2,i) = 8*(i>>2)+(i&3)+{0,4,32,36}[ct2] (A-row i=l15),
// so lane (quad,l15) emerges holding P[q=l15][m in [8q,8q+8) u [32+8q,32+8q+8)] --
// exactly its PV A-frag set. cvt_pk packs mfma outputs DIRECTLY into A-frag words:
// zero cross-lane exchange. Seg-swizzle keys on row bits 1,3 (perm freezes bit2).
// No validity mask (pad K rows = 0 -> P=1, V pad = 0; den -= 48 exact).
__global__ __launch_bounds__(256) void attn_kernel(const unsigned short* __restrict__ Qt,
                                                   const unsigned short* __restrict__ Kw,
                                                   const unsigned short* __restrict__ Vt,
                                                   unsigned short* __restrict__ Ao) {
  __shared__ unsigned short Ks[2][4096];   // [buf][2 panels [64 m][32 d]], seg-swizzled
  __shared__ unsigned short Vs[2][4096];   // [buf][2 panels [64 d][32 m]], seg-swizzled
  const int tid = threadIdx.x;
  const int w = tid >> 6, lane = tid & 63;
  const int l15 = lane & 15, quad = lane >> 4, q8 = quad * 8;
  const int bh = blockIdx.x, qt = blockIdx.y;

  // Q B-frags from Q^T[bh][d][n]: lane = q-col = l15, k-elem j of half h = d = h*32+q8+j
  short8 aq[2][2];
#pragma unroll
  for (int mq = 0; mq < 2; ++mq) {
    int qrow = qt * 128 + w * 32 + mq * 16 + l15;
    const unsigned short* Qb = Qt + (size_t)bh * D_ * N_ + qrow;
#pragma unroll
    for (int h = 0; h < 2; ++h)
#pragma unroll
      for (int j = 0; j < 8; ++j)
        aq[mq][h][j] = (short)Qb[(size_t)(h * 32 + q8 + j) * N_];
  }

  f32x4 oacc[2][4] = {};
  float den[2] = {};

  const unsigned short* Kbh = Kw + (size_t)bh * MP_ * 64;
  const unsigned short* Vbh = Vt + (size_t)bh * 64 * MP_;

  // staging: lane -> (row-in-slot = lane>>2); source seg inverse-swizzled on row bits
  // 1,3 of LDS row R = w*16+(lane>>2): bit1 = lane bit3, bit3 = lane bit5.
  const int mrow = w * 16 + (lane >> 2);
  const int sw2 = (lane & 3) ^ (((lane >> 3) & 1) | (((lane >> 5) & 1) << 1));
  // K-frag read: permuted row base (R bits 1,3 = l15 bits 1,2); V-frag: straight rows
  const int krow = ((l15 >> 2) << 3) + (l15 & 3);
  const int qk_off = (quad ^ (((l15 >> 1) & 1) | (((l15 >> 2) & 1) << 1))) << 4;
  const int qv_off = (quad ^ (((l15 >> 1) & 1) | (((l15 >> 3) & 1) << 1))) << 4;

#define STAGE_KV(CH, BUF) {                                                    \
    _Pragma("unroll") for (int r = 0; r < 2; ++r) {                            \
      async_cp16(&Ks[BUF][r * 2048 + w * 512],                                 \
                 Kbh + (size_t)((CH) * 64 + mrow) * 64 + r * 32 + sw2 * 8);    \
      async_cp16(&Vs[BUF][r * 2048 + w * 512],                                 \
                 Vbh + (size_t)mrow * MP_ + (CH) * 64 + r * 32 + sw2 * 8);     \
    } }

  STAGE_KV(0, 0);

  union PAB { unsigned int u[4]; short8 s8; };

#pragma unroll 1
  for (int ch = 0; ch < 17; ++ch) {
    __syncthreads();   // vmcnt(0)+lgkmcnt(0)+barrier: buf[ch&1] landed for ALL waves;
                       // all waves finished reading buf[(ch+1)&1] in their iter ch-1
    if (ch + 1 < 17) STAGE_KV(ch + 1, (ch + 1) & 1);   // latency hides under compute(ch)

    const char* Kb = (const char*)&Ks[ch & 1][0];
    const char* Vb = (const char*)&Vs[ch & 1][0];

    // QK^T (swapped, permuted): output lane (quad,l15) reg r = P[q=l15][m=8q+r+c[ct2]]
    PAB apu[2][2];
#pragma unroll
    for (int ct2 = 0; ct2 < 4; ++ct2) {
      const int cc = (ct2 & 1) * 4 + (ct2 >> 1) * 32;      // {0,4,32,36}
      short8 k0 = *(const short8*)(Kb + (krow + cc) * 64 + qk_off);          // d 0..31
      short8 k1 = *(const short8*)(Kb + 4096 + (krow + cc) * 64 + qk_off);   // d 32..63
#pragma unroll
      for (int mq = 0; mq < 2; ++mq) {
        f32x4 s = {};
        s = __builtin_amdgcn_mfma_f32_16x16x32_bf16(k0, aq[mq][0], s, 0, 0, 0);
        s = __builtin_amdgcn_mfma_f32_16x16x32_bf16(k1, aq[mq][1], s, 0, 0, 0);
        float p0 = exp2_hw(s[0]), p1 = exp2_hw(s[1]);
        float p2 = exp2_hw(s[2]), p3 = exp2_hw(s[3]);
        den[mq] += (p0 + p1) + (p2 + p3);
        apu[mq][ct2 >> 1].u[(ct2 & 1) * 2]     = cvt_pk_bf16(p0, p1);
        apu[mq][ct2 >> 1].u[(ct2 & 1) * 2 + 1] = cvt_pk_bf16(p2, p3);
      }
    }

    // PV: A=P (rows=q, k=m lane-local), B=V^T (cols=d); panel h covers m in [32h,32h+32)
#pragma unroll
    for (int dt = 0; dt < 4; ++dt) {
      short8 b0 = *(const short8*)(Vb + (dt * 16 + l15) * 64 + qv_off);          // m 0..31
      short8 b1 = *(const short8*)(Vb + 4096 + (dt * 16 + l15) * 64 + qv_off);   // m 32..63
#pragma unroll
      for (int mq = 0; mq < 2; ++mq) {
        oacc[mq][dt] = __builtin_amdgcn_mfma_f32_16x16x32_bf16(apu[mq][0].s8, b0, oacc[mq][dt], 0, 0, 0);
        oacc[mq][dt] = __builtin_amdgcn_mfma_f32_16x16x32_bf16(apu[mq][1].s8, b1, oacc[mq][dt], 0, 0, 0);
      }
    }
  }
#undef STAGE_KV

  // den: each lane holds the partial over its own m-set for q=l15; quads partition m.
#pragma unroll
  for (int mq = 0; mq < 2; ++mq) {
    float d2 = den[mq];
    d2 += __shfl_xor(d2, 16);
    d2 += __shfl_xor(d2, 32);
    den[mq] = d2 - 48.0f;      // remove exp2(0)=1 from the 48 zero-pad rows (exact)
  }

  // broadcast den to output layout (row = quad*4+r) and normalize
  float rin[2][4];
#pragma unroll
  for (int mq = 0; mq < 2; ++mq)
#pragma unroll
    for (int r = 0; r < 4; ++r)
      rin[mq][r] = 1.f / __shfl(den[mq], quad * 4 + r);

  int b = bh >> 4, h = bh & 15;
#pragma unroll
  for (int mq = 0; mq < 2; ++mq)
#pragma unroll
    for (int dt = 0; dt < 4; ++dt)
#pragma unroll
      for (int r = 0; r < 4; ++r) {
        int qrow = qt * 128 + w * 32 + mq * 16 + quad * 4 + r;
        size_t dst = ((size_t)(b * N_ + qrow)) * C_ + h * 64 + dt * 16 + l15;
        Ao[dst] = f2bf(oacc[mq][dt][r] * rin[mq][r]);
      }
}

// ---------------- launch ----------------

extern "C" void kernel_launch(void* const* d_in, const int* in_sizes, int n_in,
                              void* d_out, int out_size, void* d_ws, size_t ws_size,
                              hipStream_t stream) {
  const float* x      = (const float*)d_in[0];
  const float* pk     = (const float*)d_in[1];
  const float* pv     = (const float*)d_in[2];
  const float* w_qkv  = (const float*)d_in[3];
  const float* w_proj = (const float*)d_in[4];
  const float* b_proj = (const float*)d_in[5];

  char* ws = (char*)d_ws;
  unsigned short* xb     = (unsigned short*)(ws);                 // 33,554,432 B
  unsigned short* wqkvT  = (unsigned short*)(ws + 33554432);      //  6,291,456 B
  unsigned short* wprojT = (unsigned short*)(ws + 39845888);      //  2,097,152 B
  unsigned short* Qt     = (unsigned short*)(ws + 41943040);      // 33,554,432 B
  unsigned short* Kw     = (unsigned short*)(ws + 75497472);      // 35,651,584 B
  unsigned short* Vt     = (unsigned short*)(ws + 111149056);     // 35,651,584 B
  unsigned short* attn   = xb;  // alias: xb is dead after the QKV GEMM

  prep_kernel<<<20480, 256, 0, stream>>>(x, pk, pv, xb, Kw, Vt);
  transpose_cast_kernel<<<dim3(64, 16), 256, 0, stream>>>(w_qkv, w_proj, wqkvT, wprojT);

  gemm256<0><<<dim3(64, 12), 1024, 0, stream>>>(xb, wqkvT, Qt, Kw, Vt, nullptr, nullptr);
  attn_kernel<<<dim3(256, 8), 256, 0, stream>>>(Qt, Kw, Vt, attn);
  gemm256<1><<<dim3(64, 4), 1024, 0, stream>>>(attn, wprojT, nullptr, nullptr, nullptr,
                                               b_proj, (float*)d_out);
}